// Round 12
// baseline (323.173 us; speedup 1.0000x reference)
//
#include <hip/hip_runtime.h>
#include <hip/hip_bf16.h>

// y = (spikes @ V) @ U^T — fused single-pass version.
// spikes: [4096, 16384] f32, V: [16384, 32] f32, U: [16384, 32] f32
// y: [4096, 16384] f32. Mask inputs are dead in the reference.
//
// r12: overlap reads and writes. 256 blocks x 16 rows; rows split into 4
// quarters. Quarter q: deep-convoy DMA read of spikes (1 KB/instr, r9-proven)
// accumulating z[4][32] via MFMA, while SIMULTANEOUSLY writing y for quarter
// q-1 (MFMA: A = z-fragment in registers, B = U pre-packed bf16 from L2).
// DRAM sees mixed R+W traffic for ~3/4 of the kernel (copy ubench proves
// ~3.15+3.15 TB/s concurrent R/W); previously read phase (110us) and write
// phase (45us) were fully serialized.

#define B_DIM 4096
#define NPRE  16384
#define NPOST 16384
#define RDIM  32

#define NH    4                      // row-quarters per block
#define RH    4                      // rows per quarter
#define TILEK 512                    // k per LDS tile (2 KB/row)
#define NT1   (NPRE / TILEK)         // 32 tiles per quarter
#define ROWB  2048                   // bytes per row per tile
#define ABUFB (RH * ROWB)            // 8 KB per buffer
#define NJT   (NPOST / 16)           // 1024 y col-tiles
#define JPW   (NJT / 8)              // 128 per wave
#define JPI   (JPW / NT1)            // 4 y-tiles per wave per mixed iter

typedef __attribute__((ext_vector_type(8))) short short8;   // 8 bf16
typedef __attribute__((ext_vector_type(4))) float f32x4;
typedef const __attribute__((address_space(1))) void GAS;
typedef __attribute__((address_space(3))) void LAS;

static __device__ __forceinline__ unsigned pack_bf2(float lo, float hi) {
    union { __hip_bfloat162 h; unsigned u; } c;
    c.h = __float22bfloat162_rn(make_float2(lo, hi));   // v_cvt_pk_bf16_f32
    return c.u;
}

// ---- V packing (proven r4): vpack[((kt*2+half)*64 + lane)*8 + e]
//      = bf16(V[kt*32 + (lane>>4)*8 + e][half*16 + (lane&15)])
__global__ void vpack_kernel(const float* __restrict__ V, short* __restrict__ vpack)
{
    const int tid  = blockIdx.x * 256 + threadIdx.x;   // 65536
    const int lane = tid & 63;
    const int half = (tid >> 6) & 1;
    const int kt   = tid >> 7;
    const int n    = half * 16 + (lane & 15);
    const int k0   = kt * 32 + (lane >> 4) * 8;
    union { short8 s; short el[8]; } f;
    #pragma unroll
    for (int e = 0; e < 8; ++e) {
        union { __hip_bfloat16 h; short s; } c;
        c.h = __float2bfloat16(V[(size_t)(k0 + e) * RDIM + n]);
        f.el[e] = c.s;
    }
    *reinterpret_cast<short8*>(vpack + (size_t)tid * 8) = f.s;
}

// ---- U packing (B-frag order for y = z @ U^T):
// upack[(jt*64 + lane)*8 + e] = bf16(U[jt*16 + (lane&15)][(lane>>4)*8 + e])
__global__ void upack_kernel(const float* __restrict__ U, short* __restrict__ upack)
{
    const int tid  = blockIdx.x * 256 + threadIdx.x;   // 65536
    const int lane = tid & 63;
    const int jt   = tid >> 6;
    union { short8 s; short el[8]; } f;
    #pragma unroll
    for (int e = 0; e < 8; ++e) {
        union { __hip_bfloat16 h; short s; } c;
        c.h = __float2bfloat16(U[(size_t)(jt * 16 + (lane & 15)) * RDIM + (lane >> 4) * 8 + e]);
        f.el[e] = c.s;
    }
    *reinterpret_cast<short8*>(upack + (size_t)tid * 8) = f.s;
}

// ---- fused: per block 16 rows; 4 quarters pipelined read||write -----------
__global__ __launch_bounds__(512) void fused_kernel(
    const float* __restrict__ spikes, const short* __restrict__ vpack,
    const short* __restrict__ upack, float* __restrict__ y)
{
    __shared__ char  abuf[2][ABUFB];       // 16 KB A double-buffer
    __shared__ float red[8][RH][RDIM];     // 4 KB cross-wave partials
    __shared__ float zbuf[RH][RDIM];       // 512 B reduced z

    const int tid  = threadIdx.x;
    const int lane = tid & 63;
    const int w    = tid >> 6;             // wave 0..7
    const int brow = blockIdx.x * 16;

    const int m  = lane & 15;
    const int kg = lane >> 4;
    const int mr = m & 3;                  // A row within quarter

    // DMA: wave w stages row (w>>1), KB-half (w&1); source granule-XOR
    // pre-swizzled (rule 21: LDS dest stays linear).
    const int rw   = w >> 1, hw = w & 1;
    const int swz  = (lane & ~7) | ((lane & 7) ^ rw);
    const int ldst = rw * ROWB + hw * 1024;

    // A-frag LDS offsets (k-step = 2w+p): granule 8*ks + 2kg (+1), low3 XOR row
    int offA[2][2];
    #pragma unroll
    for (int p = 0; p < 2; ++p) {
        const int ks = 2 * w + p;
        offA[p][0] = mr * ROWB + (8 * ks + ((2 * kg)     ^ mr)) * 16;
        offA[p][1] = mr * ROWB + (8 * ks + ((2 * kg + 1) ^ mr)) * 16;
    }

    union { short8 s; unsigned u[4]; } zf;   // z A-fragment (persists across quarters)
    zf.u[0] = zf.u[1] = zf.u[2] = zf.u[3] = 0;

#define P2TILE(HP, JT) do {                                                   \
        const int jt_ = (JT);                                                 \
        const short8 bU = *reinterpret_cast<const short8*>(                   \
            upack + (size_t)jt_ * 512 + lane * 8);                            \
        f32x4 c_ = {0.f, 0.f, 0.f, 0.f};                                      \
        c_ = __builtin_amdgcn_mfma_f32_16x16x32_bf16(zf.s, bU, c_, 0, 0, 0);  \
        if (lane < 16) {                                                      \
            float* yp_ = y + (size_t)(brow + (HP) * RH) * NPOST               \
                           + (size_t)jt_ * 16 + lane;                         \
            _Pragma("unroll")                                                 \
            for (int j = 0; j < 4; ++j) yp_[(size_t)j * NPOST] = c_[j];       \
        }                                                                     \
    } while (0)

    // one quarter: read+accumulate z (convoy DMA), optional P2 of prev quarter
    auto p1body = [&](int h, bool with_p2) {
        const float* gA = spikes + (size_t)(brow + h * RH + rw) * NPRE
                                 + hw * 256 + swz * 4;
        __builtin_amdgcn_global_load_lds((GAS*)gA, (LAS*)(abuf[0] + ldst), 16, 0, 0);

        f32x4 acc0 = {0.f, 0.f, 0.f, 0.f};
        f32x4 acc1 = {0.f, 0.f, 0.f, 0.f};

        #pragma unroll 1
        for (int t = 0; t < NT1; ++t) {
            __syncthreads();               // tile t resident (vmcnt drained)
            if (t + 1 < NT1)
                __builtin_amdgcn_global_load_lds(
                    (GAS*)(gA + (size_t)(t + 1) * TILEK),
                    (LAS*)(abuf[(t + 1) & 1] + ldst), 16, 0, 0);

            const char* base = abuf[t & 1];
            #pragma unroll
            for (int p = 0; p < 2; ++p) {
                const int kt = t * 16 + 2 * w + p;
                const short* bt = vpack + (size_t)kt * 1024 + lane * 8;
                const short8 b0 = *reinterpret_cast<const short8*>(bt);
                const short8 b1 = *reinterpret_cast<const short8*>(bt + 512);
                const f32x4 al = *reinterpret_cast<const f32x4*>(base + offA[p][0]);
                const f32x4 ah = *reinterpret_cast<const f32x4*>(base + offA[p][1]);
                union { short8 s; unsigned u[4]; } af;
                af.u[0] = pack_bf2(al.x, al.y);
                af.u[1] = pack_bf2(al.z, al.w);
                af.u[2] = pack_bf2(ah.x, ah.y);
                af.u[3] = pack_bf2(ah.z, ah.w);
                acc0 = __builtin_amdgcn_mfma_f32_16x16x32_bf16(af.s, b0, acc0, 0, 0, 0);
                acc1 = __builtin_amdgcn_mfma_f32_16x16x32_bf16(af.s, b1, acc1, 0, 0, 0);
            }

            if (with_p2) {                 // y-tiles of quarter h-1 (writes fly
                #pragma unroll             // under this quarter's DMA reads)
                for (int q = 0; q < JPI; ++q)
                    P2TILE(h - 1, w * JPW + t * JPI + q);
            }
        }

        // cross-wave reduce: valid C rows = kg*4+j with kg==0 (rows 0..3)
        __syncthreads();
        if (lane < 16) {
            #pragma unroll
            for (int j = 0; j < 4; ++j) {
                red[w][j][lane]      = acc0[j];
                red[w][j][16 + lane] = acc1[j];
            }
        }
        __syncthreads();
        if (tid < 128) {
            const int rr = tid >> 5, cc = tid & 31;
            float s = 0.f;
            #pragma unroll
            for (int ww = 0; ww < 8; ++ww) s += red[ww][rr][cc];
            zbuf[rr][cc] = s;
        }
        __syncthreads();
        #pragma unroll
        for (int i = 0; i < 4; ++i)
            zf.u[i] = pack_bf2(zbuf[mr][kg * 8 + 2 * i], zbuf[mr][kg * 8 + 2 * i + 1]);
    };

    p1body(0, false);                      // head: pure read
    p1body(1, true);                       // mixed: read q1 || write y(q0)
    p1body(2, true);
    p1body(3, true);

    #pragma unroll 4                       // tail: pure write y(q3)
    for (int i = 0; i < JPW; ++i) P2TILE(3, w * JPW + i);

#undef P2TILE
}

extern "C" void kernel_launch(void* const* d_in, const int* in_sizes, int n_in,
                              void* d_out, int out_size, void* d_ws, size_t ws_size,
                              hipStream_t stream)
{
    const float* spikes = (const float*)d_in[0];   // [4096, 16384]
    const float* U      = (const float*)d_in[1];   // [16384, 32]
    const float* V      = (const float*)d_in[2];   // [16384, 32]

    float* y     = (float*)d_out;
    // packs live in d_ws (2 MB needed): d_out is written concurrently now.
    short* vpack = (short*)d_ws;                   // 1 MB
    short* upack = vpack + (size_t)512 * 1024;     // 1 MB

    vpack_kernel<<<256, 256, 0, stream>>>(V, vpack);
    upack_kernel<<<256, 256, 0, stream>>>(U, upack);
    fused_kernel<<<B_DIM / 16, 512, 0, stream>>>(spikes, vpack, upack, y);
}

// Round 13
// 299.816 us; speedup vs baseline: 1.0779x; 1.0779x over previous
//
#include <hip/hip_runtime.h>
#include <hip/hip_bf16.h>

// y = (spikes @ V) @ U^T
// spikes: [4096, 16384] f32, V: [16384, 32] f32, U: [16384, 32] f32
// y: [4096, 16384] f32. Mask inputs are dead in the reference.
//
// r13: launch-level R/W overlap with role-split blocks.
//   L1: Z(rows 0..2047)            — 256 z-blocks (8 rows each), all CUs read
//   L2: Z(2048..4095) || Y(0..2047)— 256 z-blocks + 256 y-blocks on other CUs
//   L3: Y(2048..4095)              — 256 y-blocks, all CUs write
// z-blocks: r11 counted-vmcnt 4-buffer DMA pipeline (48 KB/CU outstanding).
// y-blocks: proven coalesced full-wave stores; U per-thread 128B from L2.

#define B_DIM 4096
#define NPRE  16384
#define NPOST 16384
#define RDIM  32

#define NT8   32                 // tiles per z-block (K / 512)
#define RB8   2064               // LDS bytes per row (2048 + 16 pad)
#define BUF8  (8 * RB8)          // 16512 B per buffer; 4 buffers = 66 KB

typedef __attribute__((ext_vector_type(8))) short short8;   // 8 bf16
typedef __attribute__((ext_vector_type(4))) float f32x4;
typedef const __attribute__((address_space(1))) void GAS;
typedef __attribute__((address_space(3))) void LAS;

static __device__ __forceinline__ unsigned pack_bf2(float lo, float hi) {
    union { __hip_bfloat162 h; unsigned u; } c;
    c.h = __float22bfloat162_rn(make_float2(lo, hi));   // v_cvt_pk_bf16_f32
    return c.u;
}

// ---- V packing (proven r4): vpack[((kt*2+half)*64 + lane)*8 + e]
//      = bf16(V[kt*32 + (lane>>4)*8 + e][half*16 + (lane&15)])
__global__ void vpack_kernel(const float* __restrict__ V, short* __restrict__ vpack)
{
    const int tid  = blockIdx.x * 256 + threadIdx.x;   // 65536
    const int lane = tid & 63;
    const int half = (tid >> 6) & 1;
    const int kt   = tid >> 7;
    const int n    = half * 16 + (lane & 15);
    const int k0   = kt * 32 + (lane >> 4) * 8;
    union { short8 s; short el[8]; } f;
    #pragma unroll
    for (int e = 0; e < 8; ++e) {
        union { __hip_bfloat16 h; short s; } c;
        c.h = __float2bfloat16(V[(size_t)(k0 + e) * RDIM + n]);
        f.el[e] = c.s;
    }
    *reinterpret_cast<short8*>(vpack + (size_t)tid * 8) = f.s;
}

// ---- role kernel: blocks [0,nz) = z-role, blocks [nz,grid) = y-role -------
__global__ __launch_bounds__(512) void role_kernel(
    const float* __restrict__ spikes, const short* __restrict__ vpack,
    const float* __restrict__ U, float* __restrict__ z, float* __restrict__ y,
    int nz, int zrow0, int yrow0)
{
    __shared__ char smem[4 * BUF8];    // 66 KB (y-role ignores; 1 z + 1 y per CU)

    const int tid  = threadIdx.x;
    const int lane = tid & 63;
    const int w    = tid >> 6;         // wave 0..7

    if (blockIdx.x < nz) {
        // ================= z-role: 8 rows x full K ========================
        const int brow = zrow0 + blockIdx.x * 8;
        const int m  = lane & 15;
        const int kg = lane >> 4;
        const int m8 = m & 7;

        // DMA: wave w streams row w; 2 x 1KB instr per 2KB tile-slice
        const float* g0 = spikes + (size_t)(brow + w) * NPRE + lane * 4;
        const int d0 = w * RB8, d1 = w * RB8 + 1024;

        f32x4 acc0 = {0.f, 0.f, 0.f, 0.f};
        f32x4 acc1 = {0.f, 0.f, 0.f, 0.f};

#define STAGE8(T) do { char* b_ = smem + (((T) & 3) * BUF8);                  \
        __builtin_amdgcn_global_load_lds((GAS*)(g0 + (size_t)(T) * 512),      \
                                         (LAS*)(b_ + d0), 16, 0, 0);          \
        __builtin_amdgcn_global_load_lds((GAS*)(g0 + (size_t)(T) * 512 + 256),\
                                         (LAS*)(b_ + d1), 16, 0, 0);          \
    } while (0)

#define COMPUTE8(T) do {                                                      \
        const char* sb_ = smem + (((T) & 3) * BUF8) + m8 * RB8;               \
        _Pragma("unroll")                                                     \
        for (int p = 0; p < 2; ++p) {                                         \
            const int ks = 2 * w + p;                                         \
            const int kt = (T) * 16 + ks;                                     \
            const short* bt = vpack + (size_t)kt * 1024 + lane * 8;           \
            const short8 b0 = *reinterpret_cast<const short8*>(bt);           \
            const short8 b1 = *reinterpret_cast<const short8*>(bt + 512);     \
            const f32x4 al = *reinterpret_cast<const f32x4*>(sb_ + ks * 128 + kg * 32);      \
            const f32x4 ah = *reinterpret_cast<const f32x4*>(sb_ + ks * 128 + kg * 32 + 16); \
            union { short8 s; unsigned u[4]; } af;                            \
            af.u[0] = pack_bf2(al.x, al.y);                                   \
            af.u[1] = pack_bf2(al.z, al.w);                                   \
            af.u[2] = pack_bf2(ah.x, ah.y);                                   \
            af.u[3] = pack_bf2(ah.z, ah.w);                                   \
            acc0 = __builtin_amdgcn_mfma_f32_16x16x32_bf16(af.s, b0, acc0, 0, 0, 0); \
            acc1 = __builtin_amdgcn_mfma_f32_16x16x32_bf16(af.s, b1, acc1, 0, 0, 0); \
        }                                                                     \
    } while (0)

        STAGE8(0); STAGE8(1); STAGE8(2);   // 3 tiles in flight (6 loads/wave)

        #pragma unroll 1
        for (int t = 0; t < NT8 - 3; ++t) {
            asm volatile("s_waitcnt vmcnt(4)" ::: "memory");  // own tile-t loads done
            __builtin_amdgcn_s_barrier();                     // all waves' tile t done
            __builtin_amdgcn_sched_barrier(0);
            STAGE8(t + 3);                                    // never drain to 0
            COMPUTE8(t);
        }
        asm volatile("s_waitcnt vmcnt(4)" ::: "memory");
        __builtin_amdgcn_s_barrier();
        __builtin_amdgcn_sched_barrier(0);
        COMPUTE8(NT8 - 3);
        asm volatile("s_waitcnt vmcnt(2)" ::: "memory");
        __builtin_amdgcn_s_barrier();
        __builtin_amdgcn_sched_barrier(0);
        COMPUTE8(NT8 - 2);
        asm volatile("s_waitcnt vmcnt(0)" ::: "memory");
        __builtin_amdgcn_s_barrier();
        __builtin_amdgcn_sched_barrier(0);
        COMPUTE8(NT8 - 1);

#undef STAGE8
#undef COMPUTE8

        // ---- cross-wave reduce: valid C rows 0..7 (kg<2), n = m / 16+m ----
        __syncthreads();
        float* red = reinterpret_cast<float*>(smem);   // [8][8][32] = 8 KB
        if (kg < 2) {
            float* rw = red + w * 256;
            #pragma unroll
            for (int j = 0; j < 4; ++j) {
                rw[(kg * 4 + j) * RDIM + m]      = acc0[j];
                rw[(kg * 4 + j) * RDIM + 16 + m] = acc1[j];
            }
        }
        __syncthreads();
        if (tid < 256) {                   // 8 rows x 32 r
            float s = 0.f;
            #pragma unroll
            for (int ww = 0; ww < 8; ++ww) s += red[ww * 256 + tid];
            z[(size_t)(brow + (tid >> 5)) * RDIM + (tid & 31)] = s;
        }
    } else {
        // ================= y-role: 8 rows x full NPOST ====================
        const int yb   = blockIdx.x - nz;
        const int row0 = yrow0 + yb * 8;

        #pragma unroll 1
        for (int jb = 0; jb < NPOST / 512; ++jb) {
            const int col = jb * 512 + tid;
            float u[RDIM];
            #pragma unroll
            for (int q = 0; q < 8; ++q) {
                const float4 v = *reinterpret_cast<const float4*>(
                    &U[(size_t)col * RDIM + q * 4]);
                u[q * 4 + 0] = v.x; u[q * 4 + 1] = v.y;
                u[q * 4 + 2] = v.z; u[q * 4 + 3] = v.w;
            }
            #pragma unroll
            for (int row = 0; row < 8; ++row) {
                const float* zr = &z[(size_t)(row0 + row) * RDIM];  // uniform -> s_load
                float a0 = 0.f, a1 = 0.f, a2 = 0.f, a3 = 0.f;
                #pragma unroll
                for (int r = 0; r < RDIM; r += 4) {
                    a0 += zr[r + 0] * u[r + 0];
                    a1 += zr[r + 1] * u[r + 1];
                    a2 += zr[r + 2] * u[r + 2];
                    a3 += zr[r + 3] * u[r + 3];
                }
                y[(size_t)(row0 + row) * NPOST + col] = (a0 + a1) + (a2 + a3);
            }
        }
    }
}

extern "C" void kernel_launch(void* const* d_in, const int* in_sizes, int n_in,
                              void* d_out, int out_size, void* d_ws, size_t ws_size,
                              hipStream_t stream)
{
    const float* spikes = (const float*)d_in[0];   // [4096, 16384]
    const float* U      = (const float*)d_in[1];   // [16384, 32]
    const float* V      = (const float*)d_in[2];   // [16384, 32]

    float* y     = (float*)d_out;
    short* vpack = (short*)d_ws;                           // 1 MB
    float* z     = (float*)((char*)d_ws + (1 << 20));      // 512 KB

    vpack_kernel<<<256, 256, 0, stream>>>(V, vpack);
    // L1: pure read half0
    role_kernel<<<256, 512, 0, stream>>>(spikes, vpack, U, z, y, 256, 0, 0);
    // L2: read half1 || write half0
    role_kernel<<<512, 512, 0, stream>>>(spikes, vpack, U, z, y, 256, 2048, 0);
    // L3: pure write half1
    role_kernel<<<256, 512, 0, stream>>>(spikes, vpack, U, z, y, 0, 0, 2048);
}

// Round 14
// 181.912 us; speedup vs baseline: 1.7765x; 1.6481x over previous
//
#include <hip/hip_runtime.h>
#include <hip/hip_bf16.h>

// y = (spikes @ V) @ U^T
// spikes: [4096, 16384] f32, V: [16384, 32] f32, U: [16384, 32] f32
// y: [4096, 16384] f32. Mask inputs are dead in the reference.
//
// r14: cut vmem LOAD bytes. Model (fits r4-r13): per-CU load path caps at
// ~9.5 B/cyc (~5 TB/s chip) regardless of hit level; prior zparts moved
// 268MB A + 268MB B(vpack re-read per 16-row block) = 536MB -> ~107us.
// Here blocks = 32 rows x K/2: B amortized over 2x rows -> 268+128 = 396MB.
// Machinery unchanged from r11 (proven): counted-vmcnt deep DMA pipeline,
// granule-XOR A swizzle, in-kernel cross-wave reduce.

#define B_DIM 4096
#define NPRE  16384
#define NPOST 16384
#define RDIM  32

#define NT    32                 // tiles per block: 8192 k / 256
#define TILEK 256                // k per tile (1 KB per row)
#define ABUF  32768              // A region: 32 rows x 1 KB
#define BUFB  49152              // A (32 KB) + B (16 KB) per buffer
// smem = 3 * BUFB = 144 KB -> 1 block/CU

typedef __attribute__((ext_vector_type(8))) short short8;   // 8 bf16
typedef __attribute__((ext_vector_type(4))) float f32x4;
typedef const __attribute__((address_space(1))) void GAS;
typedef __attribute__((address_space(3))) void LAS;

static __device__ __forceinline__ unsigned pack_bf2(float lo, float hi) {
    union { __hip_bfloat162 h; unsigned u; } c;
    c.h = __float22bfloat162_rn(make_float2(lo, hi));   // v_cvt_pk_bf16_f32
    return c.u;
}

// ---- V packing (proven r4): piece (kt, half) = 512 shorts at (kt*2+half)*512:
// vpack[((kt*2+half)*64 + lane)*8 + e] = bf16(V[kt*32+(lane>>4)*8+e][half*16+(lane&15)])
__global__ void vpack_kernel(const float* __restrict__ V, short* __restrict__ vpack)
{
    const int tid  = blockIdx.x * 256 + threadIdx.x;   // 65536
    const int lane = tid & 63;
    const int half = (tid >> 6) & 1;
    const int kt   = tid >> 7;
    const int n    = half * 16 + (lane & 15);
    const int k0   = kt * 32 + (lane >> 4) * 8;
    union { short8 s; short el[8]; } f;
    #pragma unroll
    for (int e = 0; e < 8; ++e) {
        union { __hip_bfloat16 h; short s; } c;
        c.h = __float2bfloat16(V[(size_t)(k0 + e) * RDIM + n]);
        f.el[e] = c.s;
    }
    *reinterpret_cast<short8*>(vpack + (size_t)tid * 8) = f.s;
}

// ---- phase A: block = 32 rows x 8192 k; wave (s=w&1, q=w>>1): strip s,
// tile-local ksteps {2q, 2q+1}. DMA per wave per tile: 4 A-rows + 2 B-pieces.
__global__ __launch_bounds__(512) void zpart_kernel(
    const float* __restrict__ spikes, const short* __restrict__ vpack,
    float* __restrict__ part)
{
    __shared__ char smem[3 * BUFB];    // 144 KB

    const int tid  = threadIdx.x;
    const int lane = tid & 63;
    const int w    = tid >> 6;         // wave 0..7
    const int s    = w & 1;            // row strip (16 rows)
    const int q    = w >> 1;           // k-quarter of tile
    const int brow  = blockIdx.x * 32;
    const int khalf = blockIdx.y;      // 0..1 (k range khalf*8192..)
    const int m  = lane & 15;
    const int kg = lane >> 4;

    // --- A DMA: wave stages rows w*4..w*4+3 (1 KB/instr), source granule-XOR
    // pre-swizzled (rule 21: LDS dest linear, read applies same XOR).
    const float* ga[4]; int la[4];
    #pragma unroll
    for (int qq = 0; qq < 4; ++qq) {
        const int row = w * 4 + qq;
        const int swz = (lane & ~7) | ((lane & 7) ^ (row & 7));
        ga[qq] = spikes + (size_t)(brow + row) * NPRE + khalf * 8192 + swz * 4;
        la[qq] = row * 1024;
    }
    // --- B DMA: wave stages kstep w of each tile (2 pieces of 1 KB)
    const short* gb = vpack + ((size_t)(khalf * 256 + w) * 2) * 512 + lane * 8;
    const int lb = ABUF + w * 2048;

    f32x4 acc0 = {0.f, 0.f, 0.f, 0.f};
    f32x4 acc1 = {0.f, 0.f, 0.f, 0.f};

#define STAGE(T) do {                                                         \
        char* b_ = smem + (((T) % 3) * BUFB);                                 \
        __builtin_amdgcn_global_load_lds((GAS*)(ga[0] + (size_t)(T) * TILEK), \
                                         (LAS*)(b_ + la[0]), 16, 0, 0);       \
        __builtin_amdgcn_global_load_lds((GAS*)(ga[1] + (size_t)(T) * TILEK), \
                                         (LAS*)(b_ + la[1]), 16, 0, 0);       \
        __builtin_amdgcn_global_load_lds((GAS*)(ga[2] + (size_t)(T) * TILEK), \
                                         (LAS*)(b_ + la[2]), 16, 0, 0);       \
        __builtin_amdgcn_global_load_lds((GAS*)(ga[3] + (size_t)(T) * TILEK), \
                                         (LAS*)(b_ + la[3]), 16, 0, 0);       \
        __builtin_amdgcn_global_load_lds((GAS*)(gb + (size_t)(T) * 8192),     \
                                         (LAS*)(b_ + lb), 16, 0, 0);          \
        __builtin_amdgcn_global_load_lds((GAS*)(gb + (size_t)(T) * 8192 + 512),\
                                         (LAS*)(b_ + lb + 1024), 16, 0, 0);   \
    } while (0)

#define COMPUTE(T) do {                                                       \
        const char* ab_ = smem + (((T) % 3) * BUFB);                          \
        _Pragma("unroll")                                                     \
        for (int p = 0; p < 2; ++p) {                                         \
            const int ks = 2 * q + p;                                         \
            const int rb_ = (s * 16 + m) * 1024;                              \
            const int g0 = ks * 8 + ((2 * kg)     ^ (m & 7));                 \
            const int g1 = ks * 8 + ((2 * kg + 1) ^ (m & 7));                 \
            const f32x4 al = *reinterpret_cast<const f32x4*>(ab_ + rb_ + g0 * 16); \
            const f32x4 ah = *reinterpret_cast<const f32x4*>(ab_ + rb_ + g1 * 16); \
            const short8 b0 = *reinterpret_cast<const short8*>(                \
                ab_ + ABUF + (ks * 2) * 1024 + lane * 16);                     \
            const short8 b1 = *reinterpret_cast<const short8*>(                \
                ab_ + ABUF + (ks * 2 + 1) * 1024 + lane * 16);                 \
            union { short8 s_; unsigned u[4]; } af;                           \
            af.u[0] = pack_bf2(al.x, al.y);                                   \
            af.u[1] = pack_bf2(al.z, al.w);                                   \
            af.u[2] = pack_bf2(ah.x, ah.y);                                   \
            af.u[3] = pack_bf2(ah.z, ah.w);                                   \
            acc0 = __builtin_amdgcn_mfma_f32_16x16x32_bf16(af.s_, b0, acc0, 0, 0, 0); \
            acc1 = __builtin_amdgcn_mfma_f32_16x16x32_bf16(af.s_, b1, acc1, 0, 0, 0); \
        }                                                                     \
    } while (0)

    // prologue: 2 tiles in flight (12 loads/wave)
    STAGE(0); STAGE(1);

    #pragma unroll 1
    for (int t = 0; t < NT - 2; ++t) {
        asm volatile("s_waitcnt vmcnt(6)" ::: "memory");  // own tile-t loads done
        __builtin_amdgcn_s_barrier();                     // => all waves' tile t done
        __builtin_amdgcn_sched_barrier(0);
        STAGE(t + 2);                                     // refill; never drain to 0
        COMPUTE(t);
    }
    asm volatile("s_waitcnt vmcnt(6)" ::: "memory");
    __builtin_amdgcn_s_barrier();
    __builtin_amdgcn_sched_barrier(0);
    COMPUTE(NT - 2);
    asm volatile("s_waitcnt vmcnt(0)" ::: "memory");
    __builtin_amdgcn_s_barrier();
    __builtin_amdgcn_sched_barrier(0);
    COMPUTE(NT - 1);

#undef STAGE
#undef COMPUTE

    // ---- cross-wave reduce over q (4 waves per strip) ---------------------
    __syncthreads();
    float* red = reinterpret_cast<float*>(smem);   // [4q][2s][16][32] = 16 KB
    {
        float* rw = red + (q * 2 + s) * 512;
        #pragma unroll
        for (int j = 0; j < 4; ++j) {
            rw[(kg * 4 + j) * RDIM + m]      = acc0[j];
            rw[(kg * 4 + j) * RDIM + 16 + m] = acc1[j];
        }
    }
    __syncthreads();
    #pragma unroll
    for (int hh = 0; hh < 2; ++hh) {
        const int e  = hh * 512 + tid;         // 1024 = 32 rows x 32 r
        const int si = e >> 9, rl = (e >> 5) & 15, cc = e & 31;
        float sum = 0.f;
        #pragma unroll
        for (int qq = 0; qq < 4; ++qq)
            sum += red[(qq * 2 + si) * 512 + rl * RDIM + cc];
        part[((size_t)khalf * B_DIM + brow + si * 16 + rl) * RDIM + cc] = sum;
    }
}

// ---- z = part[0] + part[1] ------------------------------------------------
__global__ void zreduce_kernel(const float* __restrict__ part, float* __restrict__ z)
{
    const int idx = (blockIdx.x * blockDim.x + threadIdx.x) * 4;  // 131072 floats
    const float4 a = *reinterpret_cast<const float4*>(&part[idx]);
    const float4 b = *reinterpret_cast<const float4*>(&part[(size_t)B_DIM * RDIM + idx]);
    float4 s4; s4.x = a.x + b.x; s4.y = a.y + b.y; s4.z = a.z + b.z; s4.w = a.w + b.w;
    *reinterpret_cast<float4*>(&z[idx]) = s4;
}

// ---- phase B: y[b][j] = sum_r z[b][r] * U[j][r] (proven, write-bound) -----
#define TJ 256
#define TB 64

__global__ __launch_bounds__(256) void ykernel(
    const float* __restrict__ z, const float* __restrict__ U,
    float* __restrict__ y)
{
    const int j  = blockIdx.x * TJ + threadIdx.x;
    const int b0 = blockIdx.y * TB;

    float u[RDIM];
    #pragma unroll
    for (int qq = 0; qq < 8; ++qq) {
        const float4 v = *reinterpret_cast<const float4*>(&U[(size_t)j * RDIM + qq * 4]);
        u[qq * 4 + 0] = v.x; u[qq * 4 + 1] = v.y; u[qq * 4 + 2] = v.z; u[qq * 4 + 3] = v.w;
    }

    for (int bb = 0; bb < TB; ++bb) {
        const float* zr = &z[(size_t)(b0 + bb) * RDIM];   // wave-uniform -> s_load
        float a0 = 0.f, a1 = 0.f, a2 = 0.f, a3 = 0.f;
        #pragma unroll
        for (int r = 0; r < RDIM; r += 4) {
            a0 += zr[r + 0] * u[r + 0];
            a1 += zr[r + 1] * u[r + 1];
            a2 += zr[r + 2] * u[r + 2];
            a3 += zr[r + 3] * u[r + 3];
        }
        y[(size_t)(b0 + bb) * NPOST + j] = (a0 + a1) + (a2 + a3);
    }
}

extern "C" void kernel_launch(void* const* d_in, const int* in_sizes, int n_in,
                              void* d_out, int out_size, void* d_ws, size_t ws_size,
                              hipStream_t stream)
{
    const float* spikes = (const float*)d_in[0];   // [4096, 16384]
    const float* U      = (const float*)d_in[1];   // [16384, 32]
    const float* V      = (const float*)d_in[2];   // [16384, 32]

    float* y     = (float*)d_out;
    float* part  = (float*)d_out;                  // [2][4096][32] f32 = 1 MB at
                                                   // front of d_out; consumed by
                                                   // zreduce before ykernel writes
    short* vpack = (short*)d_ws;                   // 1 MB
    float* z     = (float*)((char*)d_ws + (1 << 20));  // 512 KB

    vpack_kernel<<<256, 256, 0, stream>>>(V, vpack);
    zpart_kernel<<<dim3(B_DIM / 32, 2), 512, 0, stream>>>(spikes, vpack, part);
    zreduce_kernel<<<dim3((B_DIM * RDIM / 4) / 256), 256, 0, stream>>>(part, z);
    ykernel<<<dim3(NPOST / TJ, B_DIM / TB), 256, 0, stream>>>(z, U, y);
}

// Round 16
// 157.497 us; speedup vs baseline: 2.0519x; 1.1550x over previous
//
#include <hip/hip_runtime.h>
#include <hip/hip_bf16.h>

// y = (spikes @ V) @ U^T
// spikes: [4096, 16384] f32, V: [16384, 32] f32, U: [16384, 32] f32
// y: [4096, 16384] f32 (268 MB). Mask inputs are dead in the reference.
//
// FINAL (r11 restored): best passing configuration, 158.4 us.
//   vpack (~2us): V -> bf16 MFMA B-fragment order, 1 MB.
//   zpart (~107us): 256 blocks x 16 rows x full K. bf16 MFMA 16x16x32;
//     A + B staged via global_load_lds, 4-buffer counted-vmcnt pipeline
//     (wait vmcnt(8), never drain to 0 in the main loop), granule-XOR
//     pre-swizzled A source, in-kernel cross-wave reduce -> z.
//     Measured spikes read rate ~2.4 TB/s (~75% of m13's read-side ref).
//   ykernel (~45us): write-bound at ~6 TB/s (store floor).
// Models killed by experiment: DRAM-page granularity (r8), stream count (r9),
// L3 writeback thrash (r10), total-vmem-bytes (r14), R/W overlap (r12, r13).

#define B_DIM 4096
#define NPRE  16384
#define NPOST 16384
#define RDIM  32

#define ROWS   16
#define TILEK  256                   // k per tile (1 KB per row)
#define NTILE  (NPRE / TILEK)        // 64
#define ABYTES 16384                 // A region: 16 rows x 1024 B
#define BUFB   32768                 // A (16 KB) + B (16 KB) per buffer
// smem = 4 * BUFB = 128 KB -> 1 block/CU

typedef __attribute__((ext_vector_type(8))) short short8;   // 8 bf16
typedef __attribute__((ext_vector_type(4))) float f32x4;
typedef const __attribute__((address_space(1))) void GAS;
typedef __attribute__((address_space(3))) void LAS;

static __device__ __forceinline__ unsigned pack_bf2(float lo, float hi) {
    union { __hip_bfloat162 h; unsigned u; } c;
    c.h = __float22bfloat162_rn(make_float2(lo, hi));   // v_cvt_pk_bf16_f32
    return c.u;
}

// ---- V packing (proven r4): vpack[((kt*2+half)*64 + lane)*8 + e]
//      = bf16(V[kt*32 + (lane>>4)*8 + e][half*16 + (lane&15)])
__global__ void vpack_kernel(const float* __restrict__ V, short* __restrict__ vpack)
{
    const int tid  = blockIdx.x * 256 + threadIdx.x;   // 65536
    const int lane = tid & 63;
    const int half = (tid >> 6) & 1;
    const int kt   = tid >> 7;
    const int n    = half * 16 + (lane & 15);
    const int k0   = kt * 32 + (lane >> 4) * 8;
    union { short8 s; short el[8]; } f;
    #pragma unroll
    for (int e = 0; e < 8; ++e) {
        union { __hip_bfloat16 h; short s; } c;
        c.h = __float2bfloat16(V[(size_t)(k0 + e) * RDIM + n]);
        f.el[e] = c.s;
    }
    *reinterpret_cast<short8*>(vpack + (size_t)tid * 8) = f.s;
}

// ---- phase A: block = 16 rows x full K; wave w owns kstep w of each tile --
__global__ __launch_bounds__(512) void zpart_kernel(
    const float* __restrict__ spikes, const short* __restrict__ vpack,
    float* __restrict__ z)
{
    __shared__ char smem[4 * BUFB];    // 128 KB

    const int tid  = threadIdx.x;
    const int lane = tid & 63;
    const int w    = tid >> 6;         // wave 0..7
    const int brow = blockIdx.x * ROWS;

    const int m  = lane & 15;          // fragment batch-row
    const int kg = lane >> 4;          // k-group
    const int m7 = m & 7;

    // --- DMA descriptors (4 x 1KB per tile per wave) ---
    // A: rows 2w, 2w+1; source granule-XOR-swizzled (rule 21): LDS stays
    // linear, global src granule = (l&~7)|((l&7)^(row&7)).
    const float* ga0; const float* ga1;
    {
        const int r0 = 2 * w, r1 = 2 * w + 1;
        const int l0 = (lane & ~7) | ((lane & 7) ^ (r0 & 7));
        const int l1 = (lane & ~7) | ((lane & 7) ^ (r1 & 7));
        ga0 = spikes + (size_t)(brow + r0) * NPRE + l0 * 4;
        ga1 = spikes + (size_t)(brow + r1) * NPRE + l1 * 4;
    }
    const int laA0 = (2 * w) * 1024, laA1 = (2 * w + 1) * 1024;
    // B: pieces 2w, 2w+1 (kt = w, halves 0/1); global piece = t*16 + piece
    const short* gb0 = vpack + (size_t)(2 * w) * 512 + lane * 8;
    const short* gb1 = vpack + (size_t)(2 * w + 1) * 512 + lane * 8;
    const int laB0 = ABYTES + (2 * w) * 1024, laB1 = ABYTES + (2 * w + 1) * 1024;

    // --- compute descriptors (constant per thread) ---
    const int offA0 = m * 1024 + ((w << 3) + ((2 * kg) ^ m7)) * 16;
    const int offA1 = m * 1024 + ((w << 3) + ((2 * kg + 1) ^ m7)) * 16;
    const int offB0 = ABYTES + (2 * w) * 1024 + lane * 16;
    const int offB1 = offB0 + 1024;

    f32x4 acc0 = {0.f, 0.f, 0.f, 0.f};
    f32x4 acc1 = {0.f, 0.f, 0.f, 0.f};

#define STAGE(T) do {                                                         \
        char* base_ = smem + (((T) & 3) * BUFB);                              \
        __builtin_amdgcn_global_load_lds((GAS*)(gb0 + (size_t)(T) * 8192),    \
                                         (LAS*)(base_ + laB0), 16, 0, 0);     \
        __builtin_amdgcn_global_load_lds((GAS*)(gb1 + (size_t)(T) * 8192),    \
                                         (LAS*)(base_ + laB1), 16, 0, 0);     \
        __builtin_amdgcn_global_load_lds((GAS*)(ga0 + (size_t)(T) * TILEK),   \
                                         (LAS*)(base_ + laA0), 16, 0, 0);     \
        __builtin_amdgcn_global_load_lds((GAS*)(ga1 + (size_t)(T) * TILEK),   \
                                         (LAS*)(base_ + laA1), 16, 0, 0);     \
    } while (0)

#define COMPUTE(T) do {                                                       \
        const char* ab_ = smem + (((T) & 3) * BUFB);                          \
        const f32x4 al = *reinterpret_cast<const f32x4*>(ab_ + offA0);        \
        const f32x4 ah = *reinterpret_cast<const f32x4*>(ab_ + offA1);        \
        const short8 b0 = *reinterpret_cast<const short8*>(ab_ + offB0);      \
        const short8 b1 = *reinterpret_cast<const short8*>(ab_ + offB1);      \
        union { short8 s; unsigned u[4]; } af;                                \
        af.u[0] = pack_bf2(al.x, al.y);                                       \
        af.u[1] = pack_bf2(al.z, al.w);                                       \
        af.u[2] = pack_bf2(ah.x, ah.y);                                       \
        af.u[3] = pack_bf2(ah.z, ah.w);                                       \
        acc0 = __builtin_amdgcn_mfma_f32_16x16x32_bf16(af.s, b0, acc0, 0, 0, 0); \
        acc1 = __builtin_amdgcn_mfma_f32_16x16x32_bf16(af.s, b1, acc1, 0, 0, 0); \
    } while (0)

    // prologue: 3 tiles in flight (12 loads/wave)
    STAGE(0); STAGE(1); STAGE(2);

    #pragma unroll 1
    for (int t = 0; t < NTILE - 3; ++t) {
        asm volatile("s_waitcnt vmcnt(8)" ::: "memory");   // tile t landed (own 4)
        __builtin_amdgcn_s_barrier();                      // all waves' tile t landed
        __builtin_amdgcn_sched_barrier(0);                 // pin: no hoist across wait
        STAGE(t + 3);                                      // refill; never drain to 0
        COMPUTE(t);
    }
    // epilogue: drain 8 -> 4 -> 0
    asm volatile("s_waitcnt vmcnt(8)" ::: "memory");
    __builtin_amdgcn_s_barrier();
    __builtin_amdgcn_sched_barrier(0);
    COMPUTE(NTILE - 3);
    asm volatile("s_waitcnt vmcnt(4)" ::: "memory");
    __builtin_amdgcn_s_barrier();
    __builtin_amdgcn_sched_barrier(0);
    COMPUTE(NTILE - 2);
    asm volatile("s_waitcnt vmcnt(0)" ::: "memory");
    __builtin_amdgcn_s_barrier();
    __builtin_amdgcn_sched_barrier(0);
    COMPUTE(NTILE - 1);

#undef STAGE
#undef COMPUTE

    // ---- in-kernel cross-wave reduction: 8 partials -> z[16][32] ----------
    __syncthreads();
    float* red = reinterpret_cast<float*>(smem);   // [8][16][32] = 16 KB
    {
        float* rw = red + w * (ROWS * RDIM);
        #pragma unroll
        for (int j = 0; j < 4; ++j) {
            rw[(kg * 4 + j) * RDIM + m]      = acc0[j];
            rw[(kg * 4 + j) * RDIM + 16 + m] = acc1[j];
        }
    }
    __syncthreads();
    {
        const int e = tid;             // 512 = 16 rows x 32 r exactly
        float s = 0.f;
        #pragma unroll
        for (int ww = 0; ww < 8; ++ww) s += red[ww * (ROWS * RDIM) + e];
        z[(size_t)(brow + (e >> 5)) * RDIM + (e & 31)] = s;
    }
}

// ---- phase B: y[b][j] = sum_r z[b][r] * U[j][r] ---------------------------
#define TJ 256
#define TB 64

__global__ __launch_bounds__(256) void ykernel(
    const float* __restrict__ z, const float* __restrict__ U,
    float* __restrict__ y)
{
    const int j  = blockIdx.x * TJ + threadIdx.x;
    const int b0 = blockIdx.y * TB;

    float u[RDIM];
    #pragma unroll
    for (int q = 0; q < 8; ++q) {
        const float4 v = *reinterpret_cast<const float4*>(&U[(size_t)j * RDIM + q * 4]);
        u[q * 4 + 0] = v.x; u[q * 4 + 1] = v.y; u[q * 4 + 2] = v.z; u[q * 4 + 3] = v.w;
    }

    for (int bb = 0; bb < TB; ++bb) {
        const float* zr = &z[(size_t)(b0 + bb) * RDIM];   // wave-uniform -> s_load
        float a0 = 0.f, a1 = 0.f, a2 = 0.f, a3 = 0.f;
        #pragma unroll
        for (int r = 0; r < RDIM; r += 4) {
            a0 += zr[r + 0] * u[r + 0];
            a1 += zr[r + 1] * u[r + 1];
            a2 += zr[r + 2] * u[r + 2];
            a3 += zr[r + 3] * u[r + 3];
        }
        y[(size_t)(b0 + bb) * NPOST + j] = (a0 + a1) + (a2 + a3);
    }
}

extern "C" void kernel_launch(void* const* d_in, const int* in_sizes, int n_in,
                              void* d_out, int out_size, void* d_ws, size_t ws_size,
                              hipStream_t stream)
{
    const float* spikes = (const float*)d_in[0];   // [4096, 16384]
    const float* U      = (const float*)d_in[1];   // [16384, 32]
    const float* V      = (const float*)d_in[2];   // [16384, 32]

    float* y     = (float*)d_out;
    short* vpack = (short*)d_out;      // 1 MB at front of d_out; fully consumed
                                       // by zpart before ykernel overwrites
    float* z     = (float*)d_ws;       // 512 KB

    vpack_kernel<<<256, 256, 0, stream>>>(V, vpack);
    zpart_kernel<<<B_DIM / ROWS, 512, 0, stream>>>(spikes, vpack, z);
    ykernel<<<dim3(NPOST / TJ, B_DIM / TB), 256, 0, stream>>>(z, U, y);
}